// Round 7
// baseline (85.207 us; speedup 1.0000x reference)
//
#include <hip/hip_runtime.h>
#include <hip/hip_bf16.h>
#include <cstdint>

#define DEV static __device__ __forceinline__

typedef float        v4f __attribute__((ext_vector_type(4)));
typedef float        v2f __attribute__((ext_vector_type(2)));
typedef short        v8s __attribute__((ext_vector_type(8)));
typedef unsigned int v4u __attribute__((ext_vector_type(4)));

static constexpr int N_ENT = 100000;
static constexpr int BATCH = 4096;

DEV unsigned short f2bf(float f) {
    __hip_bfloat16 h = __float2bfloat16(f);
    return __builtin_bit_cast(unsigned short, h);
}
DEV unsigned int pkbf(float lo, float hi) {
    return (unsigned)f2bf(lo) | ((unsigned)f2bf(hi) << 16);
}
DEV float bflo(unsigned int w) { return __uint_as_float(w << 16); }
DEV float bfhi(unsigned int w) { return __uint_as_float(w & 0xffff0000u); }
DEV v2f up2(unsigned int w) { return (v2f){bflo(w), bfhi(w)}; }

// async global->LDS, 16 B per lane; LDS dest = uniform base + lane*16
DEV void glds16(const void* g, void* l) {
    __builtin_amdgcn_global_load_lds(
        (const __attribute__((address_space(1))) unsigned int*)g,
        (__attribute__((address_space(3))) unsigned int*)l, 16, 0, 0);
}

// ---------------- K0: R1b = bf16(rel @ W1[64:]); W2p/W1p packed into MFMA B-frag layout
__global__ void k0_prep(const float* __restrict__ rel, const float* __restrict__ W1,
                        const float* __restrict__ W2,
                        unsigned short* __restrict__ R1b, unsigned short* __restrict__ W2p,
                        unsigned short* __restrict__ W1p)
{
    const int gid = blockIdx.x * 256 + threadIdx.x;
    if (gid < 2048) {
        const int r = gid >> 6, j = gid & 63;
        float acc = 0.f;
        #pragma unroll 8
        for (int k = 0; k < 64; ++k)
            acc += rel[r * 64 + k] * W1[(64 + k) * 64 + j];
        R1b[gid] = f2bf(acc);
    } else if (gid < 2048 + 4096) {
        // Wp[((kk*4+tn)*64 + l)*8 + i] = bf16( W[(32kk + 8*(l>>4) + i)][16tn + (l&15)] )
        const int f = gid - 2048;
        const int i = f & 7, l = (f >> 3) & 63;
        const int tn = (f >> 9) & 3, kk = f >> 11;
        W2p[f] = f2bf(W2[(32 * kk + 8 * (l >> 4) + i) * 64 + 16 * tn + (l & 15)]);
    } else if (gid < 2048 + 8192) {
        const int f = gid - 6144;
        const int i = f & 7, l = (f >> 3) & 63;
        const int tn = (f >> 9) & 3, kk = f >> 11;
        W1p[f] = f2bf(W1[(32 * kk + 8 * (l >> 4) + i) * 64 + 16 * tn + (l & 15)]);
    }
}

// ---------------- K1: MFMA GEMM: E1 = bf16(emb @ W1[:64]); E0 = bf16(emb). 16 rows/wave.
__global__ void __launch_bounds__(256) k1_e1(const float* __restrict__ emb,
                                             const unsigned short* __restrict__ W1p,
                                             unsigned short* __restrict__ E1,
                                             unsigned short* __restrict__ E0)
{
    const int lane = threadIdx.x & 63;
    const int q = lane & 15, g = lane >> 4;
    const int wid = blockIdx.x * 4 + (threadIdx.x >> 6);
    const int e0 = wid * 16;
    if (e0 >= N_ENT) return;

    v8s af[2];
    #pragma unroll
    for (int kk = 0; kk < 2; ++kk) {
        const float* p = emb + (size_t)(e0 + q) * 64 + 32 * kk + 8 * g;
        const v4f x = *(const v4f*)p;
        const v4f y = *(const v4f*)(p + 4);
        v4u pk;
        pk[0] = pkbf(x[0], x[1]); pk[1] = pkbf(x[2], x[3]);
        pk[2] = pkbf(y[0], y[1]); pk[3] = pkbf(y[2], y[3]);
        af[kk] = __builtin_bit_cast(v8s, pk);
        *(v4u*)(E0 + (size_t)(e0 + q) * 64 + 32 * kk + 8 * g) = pk;
    }

    v4f acc[4];
    #pragma unroll
    for (int tn = 0; tn < 4; ++tn) acc[tn] = (v4f){0.f, 0.f, 0.f, 0.f};
    #pragma unroll
    for (int kk = 0; kk < 2; ++kk)
        #pragma unroll
        for (int tn = 0; tn < 4; ++tn) {
            const v8s bfr = *(const v8s*)(W1p + ((kk * 4 + tn) * 64 + lane) * 8);
            acc[tn] = __builtin_amdgcn_mfma_f32_16x16x32_bf16(af[kk], bfr, acc[tn], 0, 0, 0);
        }
    #pragma unroll
    for (int tn = 0; tn < 4; ++tn)
        #pragma unroll
        for (int i = 0; i < 4; ++i)
            E1[(size_t)(e0 + 4 * g + i) * 64 + 16 * tn + q] = f2bf(acc[tn][i]);
}

// ---------------- K2: 8 waves/block; each wave = half a combo (32 triples)
__global__ void __launch_bounds__(512) k2_fused(
    const int* __restrict__ items,
    const int* __restrict__ user_h, const int* __restrict__ user_r, const int* __restrict__ user_t,
    const int* __restrict__ item_h, const int* __restrict__ item_r, const int* __restrict__ item_t,
    const float* __restrict__ emb, const unsigned short* __restrict__ E0,
    const unsigned short* __restrict__ E1,
    const unsigned short* __restrict__ R1b, const unsigned short* __restrict__ W2p,
    const float* __restrict__ W3, float* __restrict__ out)
{
    __shared__ float ws_w[4][64];    // softmax numerators (each wave touches only its own rows)
    __shared__ float att_s[8][64];   // per-wave UNNORMALIZED t-sum partials
    __shared__ float mp[8][64];      // per-wave mean partials
    __shared__ float sden[8];        // per-wave softmax denominator partials
    __shared__ __align__(16) unsigned char e0s[8][4096];  // staged t-rows   (4 KiB/wave)
    __shared__ __align__(16) unsigned char m0s[8][2048];  // staged mean rows (2 KiB/wave)

    const int lane  = threadIdx.x & 63;
    const int w     = threadIdx.x >> 6;   // 0..7
    const int combo = w >> 1;             // 0:uL0 1:uL1 2:iL0 3:iL1
    const int hs    = w & 1;              // which half of the 64 triples
    const int layer = combo & 1;
    const int b     = blockIdx.x;

    const int* Hp; const int* Rp; const int* Tp;
    if (combo < 2) { Hp = user_h; Rp = user_r; Tp = user_t; }
    else           { Hp = item_h; Rp = item_r; Tp = item_t; }
    const int base = (layer * BATCH + b) * 64;
    const int* mH = (w >= 4 ? item_h : user_h) + b * 64;   // layer-0 heads for mean

    const int q = lane & 15, g = lane >> 4;
    const int sub = lane & 7, grp = lane >> 3;

    // ---- 1. coalesced index loads + redistribute via shfl
    const int hv  = Hp[base + lane];
    const int rv_ = Rp[base + lane];
    const int tvv = Tp[base + lane];
    const int mhv = mH[lane];
    float w3v[4];
    #pragma unroll
    for (int tn = 0; tn < 4; ++tn) w3v[tn] = W3[16 * tn + q];

    int hidx[2], ridx[2];
    #pragma unroll
    for (int tmi = 0; tmi < 2; ++tmi) {
        hidx[tmi] = __shfl(hv,  16 * (2 * hs + tmi) + q);
        ridx[tmi] = __shfl(rv_, 16 * (2 * hs + tmi) + q);
    }

    // ---- 2. register gathers for MFMA operands
    v4u ev[2][2], rvv[2][2];
    #pragma unroll
    for (int tmi = 0; tmi < 2; ++tmi)
        #pragma unroll
        for (int kk = 0; kk < 2; ++kk) {
            ev[tmi][kk]  = *(const v4u*)(E1  + (size_t)hidx[tmi] * 64 + 32 * kk + 8 * g);
            rvv[tmi][kk] = *(const v4u*)(R1b + (size_t)ridx[tmi] * 64 + 32 * kk + 8 * g);
        }

    // ---- 3. W2 B-fragments into registers (BEFORE glds so MFMA waits leave glds in flight)
    v8s bfr[2][4];
    #pragma unroll
    for (int kk = 0; kk < 2; ++kk)
        #pragma unroll
        for (int tn = 0; tn < 4; ++tn)
            bfr[kk][tn] = *(const v8s*)(W2p + ((kk * 4 + tn) * 64 + lane) * 8);

    __builtin_amdgcn_sched_barrier(0);
    // ---- 4. async LDS staging for post-softmax consumers (own wave's slice)
    #pragma unroll
    for (int it = 0; it < 4; ++it) {
        const int tr = __shfl(tvv, 32 * hs + 8 * it + grp);
        glds16(E0 + (size_t)tr * 64 + sub * 8, &e0s[w][it * 1024]);
    }
    #pragma unroll
    for (int it = 0; it < 2; ++it) {
        const int mi = __shfl(mhv, 16 * (w & 3) + 8 * it + grp);
        glds16(E0 + (size_t)mi * 64 + sub * 8, &m0s[w][it * 1024]);
    }
    __builtin_amdgcn_sched_barrier(0);

    // ---- 5. MFMA: a2 = relu(relu(E1h + R1r) @ W2); logits
    float p[2][4];
    #pragma unroll
    for (int tmi = 0; tmi < 2; ++tmi) {
        v4f a4[4];
        #pragma unroll
        for (int tn = 0; tn < 4; ++tn) a4[tn] = (v4f){0.f, 0.f, 0.f, 0.f};
        #pragma unroll
        for (int kk = 0; kk < 2; ++kk) {
            v4u afu;
            #pragma unroll
            for (int x = 0; x < 4; ++x) {
                const unsigned int e = ev[tmi][kk][x], r = rvv[tmi][kk][x];
                afu[x] = pkbf(fmaxf(bflo(e) + bflo(r), 0.f),
                              fmaxf(bfhi(e) + bfhi(r), 0.f));
            }
            const v8s af = __builtin_bit_cast(v8s, afu);
            #pragma unroll
            for (int tn = 0; tn < 4; ++tn)
                a4[tn] = __builtin_amdgcn_mfma_f32_16x16x32_bf16(af, bfr[kk][tn], a4[tn], 0, 0, 0);
        }
        #pragma unroll
        for (int i = 0; i < 4; ++i) {
            float s = 0.f;
            #pragma unroll
            for (int tn = 0; tn < 4; ++tn)
                s += fmaxf(a4[tn][i], 0.f) * w3v[tn];
            p[tmi][i] = s;
        }
    }
    #pragma unroll
    for (int m = 1; m <= 8; m <<= 1)
        #pragma unroll
        for (int tmi = 0; tmi < 2; ++tmi)
            #pragma unroll
            for (int i = 0; i < 4; ++i)
                p[tmi][i] += __shfl_xor(p[tmi][i], m);

    // ---- 6. sigmoid -> exp numerators + partial denominator (no normalization yet)
    float ee[2][4];
    float sloc = 0.f;
    #pragma unroll
    for (int tmi = 0; tmi < 2; ++tmi)
        #pragma unroll
        for (int i = 0; i < 4; ++i) {
            const float sg = 1.f / (1.f + __expf(-p[tmi][i]));
            const float ex = __expf(sg);
            ee[tmi][i] = ex;
            sloc += ex;
        }
    sloc += __shfl_xor(sloc, 16);
    sloc += __shfl_xor(sloc, 32);
    if (lane == 0) sden[w] = sloc;

    // wave-private numerator exchange (same wave writes & reads: no barrier)
    if (q == 0) {
        #pragma unroll
        for (int tmi = 0; tmi < 2; ++tmi) {
            v4f wv;
            #pragma unroll
            for (int i = 0; i < 4; ++i) wv[i] = ee[tmi][i];
            *(v4f*)&ws_w[combo][16 * (2 * hs + tmi) + 4 * g] = wv;
        }
    }

    // ---- 7. staged gathers have had the whole MFMA+softmax phase to land
    asm volatile("s_waitcnt vmcnt(0)" ::: "memory");
    __builtin_amdgcn_sched_barrier(0);

    // ---- 8. unnormalized weighted t-sum + hop-0 mean partials
    v2f a2[4], m2[4];
    #pragma unroll
    for (int c = 0; c < 4; ++c) { a2[c] = (v2f){0.f, 0.f}; m2[c] = (v2f){0.f, 0.f}; }
    #pragma unroll
    for (int it = 0; it < 4; ++it) {
        const float wgt = ws_w[combo][32 * hs + 8 * it + grp];
        const v2f wv = (v2f){wgt, wgt};
        const v4u e = *(const v4u*)&e0s[w][it * 1024 + lane * 16];
        #pragma unroll
        for (int c = 0; c < 4; ++c) a2[c] += wv * up2(e[c]);
    }
    #pragma unroll
    for (int it = 0; it < 2; ++it) {
        const v4u e = *(const v4u*)&m0s[w][it * 1024 + lane * 16];
        #pragma unroll
        for (int c = 0; c < 4; ++c) m2[c] += up2(e[c]);
    }
    #pragma unroll
    for (int m = 8; m <= 32; m <<= 1)
        #pragma unroll
        for (int c = 0; c < 4; ++c) {
            a2[c][0] += __shfl_xor(a2[c][0], m);
            a2[c][1] += __shfl_xor(a2[c][1], m);
            m2[c][0] += __shfl_xor(m2[c][0], m);
            m2[c][1] += __shfl_xor(m2[c][1], m);
        }
    if (lane < 8) {
        #pragma unroll
        for (int c = 0; c < 4; ++c) {
            att_s[w][lane * 8 + 2 * c]     = a2[c][0];
            att_s[w][lane * 8 + 2 * c + 1] = a2[c][1];
            mp[w][lane * 8 + 2 * c]        = m2[c][0];
            mp[w][lane * 8 + 2 * c + 1]    = m2[c][1];
        }
    }

    // ---- 9. item row load overlaps other waves' barrier arrival
    float itemv = 0.f;
    if (w == 0) itemv = emb[(size_t)items[b] * 64 + lane];
    __syncthreads();

    // ---- 10. final combine: apply per-combo 1/S, means, dot, sigmoid (wave 0)
    if (w == 0) {
        const float rS0 = 1.f / (sden[0] + sden[1]);
        const float rS1 = 1.f / (sden[2] + sden[3]);
        const float rS2 = 1.f / (sden[4] + sden[5]);
        const float rS3 = 1.f / (sden[6] + sden[7]);
        const int j = lane;
        const float eu = (att_s[0][j] + att_s[1][j]) * rS0
                       + (att_s[2][j] + att_s[3][j]) * rS1
                       + (mp[0][j] + mp[1][j] + mp[2][j] + mp[3][j]) * (1.f / 64.f);
        const float evv = itemv
                       + (att_s[4][j] + att_s[5][j]) * rS2
                       + (att_s[6][j] + att_s[7][j]) * rS3
                       + (mp[4][j] + mp[5][j] + mp[6][j] + mp[7][j]) * (1.f / 64.f);
        float d = eu * evv;
        #pragma unroll
        for (int m = 1; m <= 32; m <<= 1) d += __shfl_xor(d, m);
        if (lane == 0) out[b] = 1.f / (1.f + __expf(-d));
    }
}

extern "C" void kernel_launch(void* const* d_in, const int* in_sizes, int n_in,
                              void* d_out, int out_size, void* d_ws, size_t ws_size,
                              hipStream_t stream)
{
    const int*   items  = (const int*)d_in[0];
    const int*   user_h = (const int*)d_in[1];
    const int*   user_r = (const int*)d_in[2];
    const int*   user_t = (const int*)d_in[3];
    const int*   item_h = (const int*)d_in[4];
    const int*   item_r = (const int*)d_in[5];
    const int*   item_t = (const int*)d_in[6];
    const float* emb    = (const float*)d_in[7];
    const float* rel    = (const float*)d_in[8];
    const float* W1     = (const float*)d_in[9];
    const float* W2     = (const float*)d_in[10];
    const float* W3     = (const float*)d_in[11];
    float* out = (float*)d_out;

    char* ws = (char*)d_ws;
    const size_t tb = (size_t)N_ENT * 64 * 2;           // 12.8 MB per table
    unsigned short* E0  = (unsigned short*)ws;
    unsigned short* E1  = (unsigned short*)(ws + tb);
    unsigned short* R1b = (unsigned short*)(ws + 2 * tb);
    unsigned short* W2p = (unsigned short*)(ws + 2 * tb + 4096);
    unsigned short* W1p = (unsigned short*)(ws + 2 * tb + 4096 + 8192);

    hipLaunchKernelGGL(k0_prep, dim3(40), dim3(256), 0, stream, rel, W1, W2, R1b, W2p, W1p);
    hipLaunchKernelGGL(k1_e1, dim3((6250 + 3) / 4), dim3(256), 0, stream, emb, W1p, E1, E0);
    hipLaunchKernelGGL(k2_fused, dim3(BATCH), dim3(512), 0, stream,
                       items, user_h, user_r, user_t, item_h, item_r, item_t,
                       emb, E0, E1, R1b, W2p, W3, out);
}